// Round 12
// baseline (246.343 us; speedup 1.0000x reference)
//
#include <hip/hip_runtime.h>
#include <math.h>

// B=4, S=2048, D=1024, H=16, HD=64
#define SEQ 2048
#define DIM 1024
#define NH 16
#define HD 64
#define QKV_LD 3072

typedef __attribute__((ext_vector_type(8))) __bf16 bf16x8;
typedef __attribute__((ext_vector_type(8))) unsigned short u16x8;
typedef __attribute__((ext_vector_type(4))) unsigned short u16x4;
typedef __attribute__((ext_vector_type(4))) float f32x4;

// may_alias u32 for type-punned LDS writes (round-2 NaN post-mortem: TBAA
// hoisted ds_reads above ds_writes). Do NOT revert to plain int*.
typedef unsigned int __attribute__((may_alias)) u32a;

// float -> bf16 bits, round-to-nearest-even
__device__ __forceinline__ unsigned short f2b(float f) {
  unsigned int b = __builtin_bit_cast(unsigned int, f);
  return (unsigned short)((b + 0x7fffu + ((b >> 16) & 1u)) >> 16);
}

__device__ __forceinline__ void gload_lds16(const void* g, void* l) {
  __builtin_amdgcn_global_load_lds((const __attribute__((address_space(1))) void*)g,
                                   (__attribute__((address_space(3))) void*)l,
                                   16, 0, 0);
}

// alias-safe aligned 16B LDS fragment load
__device__ __forceinline__ bf16x8 ld_frag16(const unsigned short* p) {
  bf16x8 r;
  __builtin_memcpy(&r, __builtin_assume_aligned((void*)p, 16), 16);
  return r;
}

// Fine-grained barriers (AITER-style). vmcnt is a FIFO counter: with exactly
// N vmem issues per iteration per wave, vmcnt(N) = "the previous iteration's
// group has landed" while the newer group stays in flight ACROSS the barrier.
#define BARRIER_VM0()  asm volatile("s_waitcnt vmcnt(0)\ns_barrier" ::: "memory")
#define BARRIER_VM6()  asm volatile("s_waitcnt vmcnt(6)\ns_barrier" ::: "memory")
#define BARRIER_LGKM() asm volatile("s_waitcnt lgkmcnt(0)\ns_barrier" ::: "memory")
#define PH_BAR()       asm volatile("s_barrier" ::: "memory")
#define LGKM0()        asm volatile("s_waitcnt lgkmcnt(0)" ::: "memory")
#define VM0()          asm volatile("s_waitcnt vmcnt(0)" ::: "memory")
#define ISSUE_FENCE()  asm volatile("" ::: "memory")

// ---------------- fused pre-pass kernel ----------------
// Round-9: fusing 3 launches -> 1 saved ~2 us (launch-gap theory refuted;
// the ~70 us dispatch-sum-vs-total gap is harness-fixed). Kept: one less
// launch, never worse.

__device__ __forceinline__ void transpose_tile_256(
    const float* __restrict__ W, unsigned short* __restrict__ WT,
    int K, int N, int bx, int by, int tid) {
  __shared__ float tile[32][33];
  const int n0 = bx * 32, k0 = by * 32;
  const int tx = tid & 31, ty0 = tid >> 5;  // ty0 in 0..7
#pragma unroll
  for (int r = 0; r < 4; ++r)
    tile[ty0 + r * 8][tx] = W[(size_t)(k0 + ty0 + r * 8) * N + n0 + tx];
  __syncthreads();
#pragma unroll
  for (int r = 0; r < 4; ++r)
    WT[(size_t)(n0 + ty0 + r * 8) * K + k0 + tx] = f2b(tile[tx][ty0 + r * 8]);
}

__global__ __launch_bounds__(256) void prep_kernel(
    const float* __restrict__ x, unsigned short* __restrict__ xb, int n,
    const float* __restrict__ Wa, unsigned short* __restrict__ WaT,
    const float* __restrict__ Wp, unsigned short* __restrict__ WpT) {
  const int bid = blockIdx.x;
  const int tid = threadIdx.x;
  if (bid < 8192) {
    const int i = (bid * 256 + tid) * 4;
    if (i >= n) return;
    float4 v = *(const float4*)(x + i);
    u16x4 o;
    o.x = f2b(v.x); o.y = f2b(v.y); o.z = f2b(v.z); o.w = f2b(v.w);
    *(u16x4*)(xb + i) = o;
  } else if (bid < 8192 + 3072) {
    const int t = bid - 8192;                 // Wa: 96 x 32 tiles
    transpose_tile_256(Wa, WaT, DIM, 3 * DIM, t % 96, t / 96, tid);
  } else {
    const int t = bid - (8192 + 3072);        // Wp: 32 x 32 tiles
    transpose_tile_256(Wp, WpT, DIM, DIM, t % 32, t / 32, tid);
  }
}

// ---------------- GEMM v4 (2-phase counted-vmcnt) — BEST MEASURED --------
// Round-11 verified again: QKV 70.3-71.0 us, MfmaUtil 30.4, conflicts 0,
// no spills. Round-10's v5 (256-sq, monolithic 64-MFMA runs) regressed
// 69->79 (grid 384 = 1.5 unbalanced rounds + vmcnt(8) exposing the stage
// latency v4's 2-phase interleave overlaps). Structure: BM=256 BN=128
// BK=64, 512 thr / 8 waves (4x2), wave tile 64x64 (acc[4][4]).
// Triple-buffered LDS (144 KB, 1 block/CU; grid 768 = 3 BALANCED rounds),
// prefetch distance 2, two phases per K-step:
//   { 8 ds_read_b128 ; 3 gload_lds ; barrier(+vmcnt(6) on phase 1) ;
//     lgkmcnt(0) ; setprio(1) ; 16 MFMA ; setprio(0) ; barrier }
// LDS swizzle: granule g of row r at physical g^(r&7); write side via
// pre-swizzled GLOBAL source (linear gload_lds dest, rule #21); read side
// same involution. Verified conflicts 6.3M -> 0 (round 7).
// Future work (both reduced forms regressed as grafts): full m201 8-phase
// port with derived vmcnt ladder.

template <int OUT_F32>
__global__ __launch_bounds__(512, 2) void gemm_bt_v4_kernel(
    const unsigned short* __restrict__ A,
    const unsigned short* __restrict__ BT,
    const float* __restrict__ bias,
    void* __restrict__ C, int M, int N, int K,
    int scale_cols, float scale_val) {
  __shared__ __align__(16) unsigned short As[3][256 * 64];  // 3 x 32 KB
  __shared__ __align__(16) unsigned short Bs[3][128 * 64];  // 3 x 16 KB

  const int tid = threadIdx.x;
  const int wave = tid >> 6;       // 0..7
  const int lane = tid & 63;
  const int quad = lane >> 4;
  const int l16 = lane & 15;
  const int r7 = l16 & 7;
  const int m0 = blockIdx.y * 256;
  const int n0 = blockIdx.x * 128;
  const int wm = (wave >> 1) * 64;  // 0,64,128,192
  const int wn = (wave & 1) * 64;   // 0,64

  const int srow = tid >> 3;                  // 0..63
  const int sg = (tid & 7) ^ (srow & 7);      // inverse-swizzled k-granule
  const size_t a_gb = (size_t)(m0 + srow) * K + sg * 8;
  const size_t b_gb = (size_t)(n0 + srow) * K + sg * 8;

  f32x4 acc[4][4] = {};
  const int NT = K >> 6;  // K-tiles of 64

#define G_STAGE_A(kt_, buf_, j_)                                               \
  gload_lds16(A + a_gb + (size_t)(j_) * 64 * K + (size_t)(kt_) * 64,           \
              &As[buf_][(j_) * 4096 + wave * 512])
#define G_STAGE_B(kt_, buf_, j_)                                               \
  gload_lds16(BT + b_gb + (size_t)(j_) * 64 * K + (size_t)(kt_) * 64,          \
              &Bs[buf_][(j_) * 4096 + wave * 512])
#define G_STAGE_ALL(kt_, buf_)                                                 \
  {                                                                            \
    G_STAGE_A(kt_, buf_, 0); G_STAGE_A(kt_, buf_, 1);                          \
    G_STAGE_A(kt_, buf_, 2); G_STAGE_A(kt_, buf_, 3);                          \
    G_STAGE_B(kt_, buf_, 0); G_STAGE_B(kt_, buf_, 1);                          \
  }

#define V4_PHASE(kk_, la_, lb_, STAGES_, BAR_)                                 \
  {                                                                            \
    const int colg = ((((kk_) << 2) | quad) ^ r7) << 3;                        \
    bf16x8 af[4], bfr[4];                                                      \
    _Pragma("unroll") for (int i = 0; i < 4; ++i)                              \
      af[i] = ld_frag16(&(la_)[(wm + i * 16 + l16) * 64 + colg]);              \
    _Pragma("unroll") for (int i = 0; i < 4; ++i)                              \
      bfr[i] = ld_frag16(&(lb_)[(wn + i * 16 + l16) * 64 + colg]);             \
    STAGES_;                                                                   \
    BAR_;                                                                      \
    LGKM0();                                                                   \
    __builtin_amdgcn_s_setprio(1);                                             \
    _Pragma("unroll") for (int ni = 0; ni < 4; ++ni)                           \
      _Pragma("unroll") for (int mi = 0; mi < 4; ++mi)                         \
        acc[mi][ni] = __builtin_amdgcn_mfma_f32_16x16x32_bf16(                 \
            af[mi], bfr[ni], acc[mi][ni], 0, 0, 0);                            \
    __builtin_amdgcn_s_setprio(0);                                             \
    PH_BAR();                                                                  \
  }

  // prologue: tiles 0 and 1 in flight (12 issues); wait tile 0 only
  G_STAGE_ALL(0, 0);
  ISSUE_FENCE();
  G_STAGE_ALL(1, 1);
  BARRIER_VM6();

  for (int t = 0; t < NT; ++t) {
    const int pf = (t + 2 < NT) ? t + 2 : NT - 1;  // dummy-clamp keeps vmcnt exact
    const int pb = (t + 2) % 3;
    const unsigned short* la = As[t % 3];
    const unsigned short* lb = Bs[t % 3];
    V4_PHASE(0, la, lb,
             { G_STAGE_A(pf, pb, 0); G_STAGE_A(pf, pb, 1); G_STAGE_B(pf, pb, 0); },
             PH_BAR());
    V4_PHASE(1, la, lb,
             { G_STAGE_A(pf, pb, 2); G_STAGE_A(pf, pb, 3); G_STAGE_B(pf, pb, 1); },
             BARRIER_VM6());
  }

#pragma unroll
  for (int mi = 0; mi < 4; ++mi) {
#pragma unroll
    for (int ni = 0; ni < 4; ++ni) {
      const int col = n0 + wn + ni * 16 + l16;
      const int row = m0 + wm + mi * 16 + quad * 4;
      const float bv = bias[col];
      const float sv = (col < scale_cols) ? scale_val : 1.0f;
#pragma unroll
      for (int r = 0; r < 4; ++r) {
        float v = (acc[mi][ni][r] + bv) * sv;
        if (OUT_F32)
          ((float*)C)[(size_t)(row + r) * N + col] = v;
        else
          ((unsigned short*)C)[(size_t)(row + r) * N + col] = f2b(v);
      }
    }
  }
}

// ---------------- flash attention v10 (4 blocks/CU, K double-buffer) -----
// Round-12: the only large measured flash win was MORE RESIDENT BLOCKS
// (round 2: 2->3 blocks/CU, +31%). Still LDS-capped at 3/CU: 41984 B/block
// misses 4/CU by 1 KB, and 24 KB of it is the K TRIPLE-buffer that only
// exists for prefetch-distance-2. K/V is L2-resident (FETCH 29 MB, rounds
// 7/9), latency ~250 cyc << per-iter compute ~2000+ cyc, so distance-1
// hides it and the end-of-iter vmcnt(0) it requires is ~free.
//   K double-buffer: LDS 16384+8192+9216 = 33792 B -> 4 blocks/CU, and
//   grid 1024 = ONE fully-resident round. Placement is perfectly balanced
//   by construction: each CU hosts bids {b,b+256,b+512,b+768} -> qt gaps
//   of 4 -> per-CU iteration sum = 80 for every CU.
// V ping-pong collapses to a single register set (-8 VGPR). Sync proof:
//   - tile-i K in LDS: every wave's prologue/prev-iter vmcnt(0) precedes
//     the shared barrier -> all gload_lds landed before any wave reads.
//   - WAR on Ks[(i+1)&1] (= Ks[(i-1)&1]): end-of-iter BARRIER_LGKM drains
//     all waves' ds_reads before the next iteration's prefetch issues.
//   - Vt RAW: all vf ds_reads are consumed by MFMAs before the mid barrier
//     (compiler lgkm waits), so VT_WRITE after the barrier is safe.
// Tripwire: VGPR must stay <= 128 (4 waves/SIMD) — if regalloc exceeds,
// placement drops to 3 blocks and this reverts to round-11 behavior.

// prefetch global slot g_ -> Ks[g_&1] + V regs (via_, vib_)
#define FA_PREFETCH(g_, via_, vib_)                                            \
  {                                                                            \
    const int _g = (g_);                                                       \
    const int _tg = (_g < kt) ? _g : 0;                                        \
    const unsigned short* _kg =                                                \
        base + (size_t)(_tg * 64 + ktok_l) * QKV_LD + DIM + h * HD + kchunk * 8; \
    gload_lds16(_kg, &Ks[_g & 1][0][w * 512]);                                 \
    gload_lds16(_kg + 32, &Ks[_g & 1][1][w * 512]);                            \
    const unsigned short* _vg =                                                \
        base + (size_t)(_tg * 64 + 2 * vk) * QKV_LD + 2 * DIM + h * HD + vc;   \
    via_ = *(const u16x8*)_vg;                                                 \
    vib_ = *(const u16x8*)(_vg + QKV_LD);                                      \
  }

#define VT_WRITE(va_, vb_)                                                     \
  {                                                                            \
    u32a* _V32 = (u32a*)Vt;                                                    \
    _Pragma("unroll") for (int j = 0; j < 8; ++j)                              \
      _V32[vwidx[j]] = (unsigned int)(va_)[j] | ((unsigned int)(vb_)[j] << 16);\
  }

#define FA_COMPUTE(i_, t_, kt_, qf_)                                           \
  {                                                                            \
    const unsigned short* _kb0 = &Ks[(i_) & 1][0][0];                          \
    const unsigned short* _kb1 = &Ks[(i_) & 1][1][0];                          \
    bf16x8 kf0[4], kf1[4], vf0[4], vf1[4];                                     \
    _Pragma("unroll") for (int ni = 0; ni < 4; ++ni) {                         \
      const int ro = (ni * 16 + l16) * 32 + ((quad ^ rsw) * 8);                \
      kf0[ni] = ld_frag16(_kb0 + ro);                                          \
      kf1[ni] = ld_frag16(_kb1 + ro);                                          \
      vf0[ni] = ld_frag16(&Vt[quad * 512 + vroff[ni]]);                        \
      vf1[ni] = ld_frag16(&Vt[(4 + quad) * 512 + vroff[ni]]);                  \
    }                                                                          \
    const int qloc = w * 16 + quad * 4;                                        \
    __builtin_amdgcn_s_setprio(1);                                             \
    _Pragma("unroll") for (int m = 0; m < 2; ++m) {                            \
      if (!(m == 0 && (t_) == (kt_)-1)) { /* m=0 fully masked on last tile */  \
        const bool diag = ((t_) == (kt_)-2 + m);                               \
        _Pragma("unroll") for (int ni = 0; ni < 4; ++ni) {                     \
          f32x4 a = {};                                                        \
          a = __builtin_amdgcn_mfma_f32_16x16x32_bf16(qf_[m][0], kf0[ni], a, 0, 0, 0); \
          a = __builtin_amdgcn_mfma_f32_16x16x32_bf16(qf_[m][1], kf1[ni], a, 0, 0, 0); \
          const int kloc = ni * 16 + l16;                                      \
          _Pragma("unroll") for (int r = 0; r < 4; ++r) {                      \
            float p = __builtin_amdgcn_exp2f(a[r]);                            \
            if (diag && kloc > qloc + r) p = 0.0f; /* causal */                \
            Ps[w][(quad * 4 + r) * 72 + kloc] =                                \
                (unsigned short)(__builtin_bit_cast(unsigned int, p) >> 16);   \
          }                                                                    \
        }                                                                      \
        _Pragma("unroll") for (int c = 0; c < 2; ++c) {                        \
          const bf16x8 pa = ld_frag16(&Ps[w][l16 * 72 + c * 32 + quad * 8]);   \
          _Pragma("unroll") for (int ni = 0; ni < 4; ++ni)                     \
            o[m][ni] = __builtin_amdgcn_mfma_f32_16x16x32_bf16(                \
                pa, c ? vf1[ni] : vf0[ni], o[m][ni], 0, 0, 0);                 \
          lacc[m] = __builtin_amdgcn_mfma_f32_16x16x32_bf16(pa, onesb,         \
                                                            lacc[m], 0, 0, 0);\
        }                                                                      \
      }                                                                        \
    }                                                                          \
    __builtin_amdgcn_s_setprio(0);                                             \
  }

// one iteration (prefetch distance 1): issue slot i+1's group; compute tile
// i from Ks[i&1]/Vt; vmcnt(0)+barrier (slot i+1 landed — free, latency <<
// compute); publish slot i+1's V; lgkm barrier.
#define FA_ITER(i_, t_, kt_, qf_)                                              \
  {                                                                            \
    FA_PREFETCH((i_) + 1, va0, vb0);                                           \
    FA_COMPUTE(i_, t_, kt_, qf_);                                              \
    BARRIER_VM0();                                                             \
    if ((i_) + 1 < (kt_)) {                                                    \
      VT_WRITE(va0, vb0);                                                      \
      BARRIER_LGKM();                                                          \
    }                                                                          \
  }

#define FA_EPILOGUE(q0_)                                                       \
  _Pragma("unroll") for (int m = 0; m < 2; ++m)                                \
  _Pragma("unroll") for (int r = 0; r < 4; ++r) {                              \
    const float lv = __shfl(lacc[m][r], quad << 4);                            \
    const float inv = 1.0f / lv;                                               \
    const int row = (q0_) + m * 64 + w * 16 + quad * 4 + r;                    \
    unsigned short* dst = yatt + (size_t)(b * SEQ + row) * DIM + h * HD + l16; \
    _Pragma("unroll") for (int ni = 0; ni < 4; ++ni)                           \
      dst[ni * 16] = f2b(o[m][ni][r] * inv);                                   \
  }

__global__ __launch_bounds__(256, 2) void flash_kernel(
    const unsigned short* __restrict__ qkv,  // [B*S][3072] bf16 (q pre-scaled)
    unsigned short* __restrict__ yatt) {     // [B*S][1024] bf16
  __shared__ unsigned short Ks[2][2][64 * 32];             // 16384 B
  __shared__ __align__(16) unsigned short Vt[8 * 64 * 8];  //  8192 B
  __shared__ __align__(16) unsigned short Ps[4][16 * 72];  //  9216 B

  const int tid = threadIdx.x;
  const int w = tid >> 6;
  const int lane = tid & 63;
  const int quad = lane >> 4;
  const int l16 = lane & 15;

  // 1-D grid, 1024 blocks: heavy-first + same-XCD (b,h) affinity; at 4
  // blocks/CU the whole grid is resident and per-CU work is uniform (80).
  const int bid = (int)blockIdx.x;
  const int qt = 15 - (bid >> 6);  // 15..0, heavy first
  const int bh = bid & 63;
  const int b = bh >> 4;
  const int h = bh & 15;
  const int kt = 2 * qt + 2;       // 32..2
  const int q0 = qt * 128;

  const unsigned short* base = qkv + (size_t)b * SEQ * QKV_LD;

  // K staging: wave w covers toks w*16..+15, both 32-dim halves
  const int ktok_l = w * 16 + (lane >> 2);
  const int ksw = (ktok_l ^ (ktok_l >> 2)) & 3;
  const int kchunk = (lane & 3) ^ ksw;
  const int rsw = (l16 ^ (l16 >> 2)) & 3;

  // V staging: thread covers toks {2vk,2vk+1}, dims vc..vc+7
  const int vk = tid >> 3;
  const int vc = (tid & 7) * 8;
  int vwidx[8];
#pragma unroll
  for (int j = 0; j < 8; ++j)
    vwidx[j] = (vk >> 2) * 256 + (vc | ((j + (vc >> 3)) & 7)) * 4 + (vk & 3);
  int vroff[4];
#pragma unroll
  for (int ni = 0; ni < 4; ++ni) {
    const int dim = ni * 16 + l16;
    vroff[ni] = ((dim & 56) | ((dim + (dim >> 3)) & 7)) * 8;
  }

  // ones B-fragment for MFMA row-sum (B[k][0]=1 lives in l16==0 lanes)
  u16x8 ob = {};
  if (l16 == 0) {
#pragma unroll
    for (int j = 0; j < 8; ++j) ob[j] = 0x3F80;  // bf16 1.0
  }
  const bf16x8 onesb = __builtin_bit_cast(bf16x8, ob);

  // Q A-fragments up front
  bf16x8 qf[2][2];
#pragma unroll
  for (int m = 0; m < 2; ++m) {
    const unsigned short* qa =
        base + (size_t)(q0 + m * 64 + w * 16 + l16) * QKV_LD + h * HD + quad * 8;
    qf[m][0] = *(const bf16x8*)qa;
    qf[m][1] = *(const bf16x8*)(qa + 32);
  }

  // prologue: slot 0 only (distance 1); wait everything, publish V tile 0
  u16x8 va0, vb0;
  ISSUE_FENCE();
  FA_PREFETCH(0, va0, vb0);
  VM0();                 // qf + tile-0 K (this wave's) + V regs landed
  VT_WRITE(va0, vb0);    // publish V tile 0
  BARRIER_LGKM();        // all waves' K/V tile 0 visible

  f32x4 o[2][4] = {};
  f32x4 lacc[2] = {};

  for (int i = 0; i < kt; ++i) {
    FA_ITER(i, i, kt, qf);
  }
  FA_EPILOGUE(q0);
}

// ---------------- launch ----------------

extern "C" void kernel_launch(void* const* d_in, const int* in_sizes, int n_in,
                              void* d_out, int out_size, void* d_ws, size_t ws_size,
                              hipStream_t stream) {
  const float* x  = (const float*)d_in[0];   // [4,2048,1024]
  const float* Wa = (const float*)d_in[1];   // [1024,3072]
  const float* ba = (const float*)d_in[2];   // [3072]
  const float* Wp = (const float*)d_in[3];   // [1024,1024]
  const float* bp = (const float*)d_in[4];   // [1024]
  float* out = (float*)d_out;                // [4,2048,1024] fp32

  char* ws = (char*)d_ws;
  unsigned short* xb   = (unsigned short*)ws;                   // 16,777,216 B
  unsigned short* WaT  = (unsigned short*)(ws + 16777216);      //  6,291,456 B
  unsigned short* WpT  = (unsigned short*)(ws + 23068672);      //  2,097,152 B
  unsigned short* qkv  = (unsigned short*)(ws + 25165824);      // 50,331,648 B
  unsigned short* yatt = (unsigned short*)(ws + 75497472);      // 16,777,216 B

  const int M = 4 * SEQ;  // 8192
  const float qscale = 0.125f * 1.44269504089f;  // 1/sqrt(64) * log2(e)

  // fused pre-pass: 8192 (to_bf16) + 3072 (Wa^T) + 1024 (Wp^T) blocks
  prep_kernel<<<12288, 256, 0, stream>>>(x, xb, M * DIM, Wa, WaT, Wp, WpT);

  gemm_bt_v4_kernel<0><<<dim3(24, 32), 512, 0, stream>>>(xb, WaT, ba, qkv, M, 3 * DIM, DIM,
                                                         DIM, qscale);

  flash_kernel<<<dim3(1024), 256, 0, stream>>>(qkv, yatt);

  gemm_bt_v4_kernel<1><<<dim3(8, 32), 512, 0, stream>>>(yatt, WpT, bp, out, M, DIM, DIM,
                                                        0, 1.0f);
}

// Round 13
// 240.664 us; speedup vs baseline: 1.0236x; 1.0236x over previous
//
#include <hip/hip_runtime.h>
#include <math.h>

// B=4, S=2048, D=1024, H=16, HD=64
#define SEQ 2048
#define DIM 1024
#define NH 16
#define HD 64
#define QKV_LD 3072

typedef __attribute__((ext_vector_type(8))) __bf16 bf16x8;
typedef __attribute__((ext_vector_type(8))) unsigned short u16x8;
typedef __attribute__((ext_vector_type(4))) unsigned short u16x4;
typedef __attribute__((ext_vector_type(4))) float f32x4;

// may_alias u32 for type-punned LDS writes (round-2 NaN post-mortem: TBAA
// hoisted ds_reads above ds_writes). Do NOT revert to plain int*.
typedef unsigned int __attribute__((may_alias)) u32a;

// float -> bf16 bits, round-to-nearest-even
__device__ __forceinline__ unsigned short f2b(float f) {
  unsigned int b = __builtin_bit_cast(unsigned int, f);
  return (unsigned short)((b + 0x7fffu + ((b >> 16) & 1u)) >> 16);
}

__device__ __forceinline__ void gload_lds16(const void* g, void* l) {
  __builtin_amdgcn_global_load_lds((const __attribute__((address_space(1))) void*)g,
                                   (__attribute__((address_space(3))) void*)l,
                                   16, 0, 0);
}

// alias-safe aligned 16B LDS fragment load
__device__ __forceinline__ bf16x8 ld_frag16(const unsigned short* p) {
  bf16x8 r;
  __builtin_memcpy(&r, __builtin_assume_aligned((void*)p, 16), 16);
  return r;
}

// Fine-grained barriers (AITER-style). vmcnt is a FIFO counter: with exactly
// N vmem issues per iteration per wave, vmcnt(N) = "the previous iteration's
// group has landed" while the newer group stays in flight ACROSS the barrier.
#define BARRIER_VM6()  asm volatile("s_waitcnt vmcnt(6)\ns_barrier" ::: "memory")
#define BARRIER_VMLG() asm volatile("s_waitcnt vmcnt(4) lgkmcnt(0)\ns_barrier" ::: "memory")
#define BARRIER_LGKM() asm volatile("s_waitcnt lgkmcnt(0)\ns_barrier" ::: "memory")
#define PH_BAR()       asm volatile("s_barrier" ::: "memory")
#define LGKM0()        asm volatile("s_waitcnt lgkmcnt(0)" ::: "memory")
#define ISSUE_FENCE()  asm volatile("" ::: "memory")

// ---------------- fused pre-pass kernel ----------------
// Round-9: fusing 3 launches -> 1 saved ~2 us (launch-gap theory refuted;
// the ~70 us dispatch-sum-vs-total gap is harness-fixed). Kept: one less
// launch, never worse.

__device__ __forceinline__ void transpose_tile_256(
    const float* __restrict__ W, unsigned short* __restrict__ WT,
    int K, int N, int bx, int by, int tid) {
  __shared__ float tile[32][33];
  const int n0 = bx * 32, k0 = by * 32;
  const int tx = tid & 31, ty0 = tid >> 5;  // ty0 in 0..7
#pragma unroll
  for (int r = 0; r < 4; ++r)
    tile[ty0 + r * 8][tx] = W[(size_t)(k0 + ty0 + r * 8) * N + n0 + tx];
  __syncthreads();
#pragma unroll
  for (int r = 0; r < 4; ++r)
    WT[(size_t)(n0 + ty0 + r * 8) * K + k0 + tx] = f2b(tile[tx][ty0 + r * 8]);
}

__global__ __launch_bounds__(256) void prep_kernel(
    const float* __restrict__ x, unsigned short* __restrict__ xb, int n,
    const float* __restrict__ Wa, unsigned short* __restrict__ WaT,
    const float* __restrict__ Wp, unsigned short* __restrict__ WpT) {
  const int bid = blockIdx.x;
  const int tid = threadIdx.x;
  if (bid < 8192) {
    const int i = (bid * 256 + tid) * 4;
    if (i >= n) return;
    float4 v = *(const float4*)(x + i);
    u16x4 o;
    o.x = f2b(v.x); o.y = f2b(v.y); o.z = f2b(v.z); o.w = f2b(v.w);
    *(u16x4*)(xb + i) = o;
  } else if (bid < 8192 + 3072) {
    const int t = bid - 8192;                 // Wa: 96 x 32 tiles
    transpose_tile_256(Wa, WaT, DIM, 3 * DIM, t % 96, t / 96, tid);
  } else {
    const int t = bid - (8192 + 3072);        // Wp: 32 x 32 tiles
    transpose_tile_256(Wp, WpT, DIM, DIM, t % 32, t / 32, tid);
  }
}

// ---------------- GEMM v4 (2-phase counted-vmcnt) — BEST MEASURED --------
// Verified rounds 7/11: QKV 70.3-71.0 us, MfmaUtil 30.4, conflicts 0, no
// spills. v5 (256-sq monolithic) regressed; coarse 256x128 regressed.
// Structure: BM=256 BN=128 BK=64, 512 thr / 8 waves (4x2), wave tile 64x64
// (acc[4][4]). Triple-buffered LDS (144 KB, 1 block/CU; grid 768 = 3
// BALANCED rounds), prefetch distance 2, two phases per K-step:
//   { 8 ds_read_b128 ; 3 gload_lds ; barrier(+vmcnt(6) on phase 1) ;
//     lgkmcnt(0) ; setprio(1) ; 16 MFMA ; setprio(0) ; barrier }
// LDS swizzle: granule g of row r at physical g^(r&7); write side via
// pre-swizzled GLOBAL source (linear gload_lds dest, rule #21); read side
// same involution. Verified conflicts 6.3M -> 0 (round 7).

template <int OUT_F32>
__global__ __launch_bounds__(512, 2) void gemm_bt_v4_kernel(
    const unsigned short* __restrict__ A,
    const unsigned short* __restrict__ BT,
    const float* __restrict__ bias,
    void* __restrict__ C, int M, int N, int K,
    int scale_cols, float scale_val) {
  __shared__ __align__(16) unsigned short As[3][256 * 64];  // 3 x 32 KB
  __shared__ __align__(16) unsigned short Bs[3][128 * 64];  // 3 x 16 KB

  const int tid = threadIdx.x;
  const int wave = tid >> 6;       // 0..7
  const int lane = tid & 63;
  const int quad = lane >> 4;
  const int l16 = lane & 15;
  const int r7 = l16 & 7;
  const int m0 = blockIdx.y * 256;
  const int n0 = blockIdx.x * 128;
  const int wm = (wave >> 1) * 64;  // 0,64,128,192
  const int wn = (wave & 1) * 64;   // 0,64

  const int srow = tid >> 3;                  // 0..63
  const int sg = (tid & 7) ^ (srow & 7);      // inverse-swizzled k-granule
  const size_t a_gb = (size_t)(m0 + srow) * K + sg * 8;
  const size_t b_gb = (size_t)(n0 + srow) * K + sg * 8;

  f32x4 acc[4][4] = {};
  const int NT = K >> 6;  // K-tiles of 64

#define G_STAGE_A(kt_, buf_, j_)                                               \
  gload_lds16(A + a_gb + (size_t)(j_) * 64 * K + (size_t)(kt_) * 64,           \
              &As[buf_][(j_) * 4096 + wave * 512])
#define G_STAGE_B(kt_, buf_, j_)                                               \
  gload_lds16(BT + b_gb + (size_t)(j_) * 64 * K + (size_t)(kt_) * 64,          \
              &Bs[buf_][(j_) * 4096 + wave * 512])
#define G_STAGE_ALL(kt_, buf_)                                                 \
  {                                                                            \
    G_STAGE_A(kt_, buf_, 0); G_STAGE_A(kt_, buf_, 1);                          \
    G_STAGE_A(kt_, buf_, 2); G_STAGE_A(kt_, buf_, 3);                          \
    G_STAGE_B(kt_, buf_, 0); G_STAGE_B(kt_, buf_, 1);                          \
  }

#define V4_PHASE(kk_, la_, lb_, STAGES_, BAR_)                                 \
  {                                                                            \
    const int colg = ((((kk_) << 2) | quad) ^ r7) << 3;                        \
    bf16x8 af[4], bfr[4];                                                      \
    _Pragma("unroll") for (int i = 0; i < 4; ++i)                              \
      af[i] = ld_frag16(&(la_)[(wm + i * 16 + l16) * 64 + colg]);              \
    _Pragma("unroll") for (int i = 0; i < 4; ++i)                              \
      bfr[i] = ld_frag16(&(lb_)[(wn + i * 16 + l16) * 64 + colg]);             \
    STAGES_;                                                                   \
    BAR_;                                                                      \
    LGKM0();                                                                   \
    __builtin_amdgcn_s_setprio(1);                                             \
    _Pragma("unroll") for (int ni = 0; ni < 4; ++ni)                           \
      _Pragma("unroll") for (int mi = 0; mi < 4; ++mi)                         \
        acc[mi][ni] = __builtin_amdgcn_mfma_f32_16x16x32_bf16(                 \
            af[mi], bfr[ni], acc[mi][ni], 0, 0, 0);                            \
    __builtin_amdgcn_s_setprio(0);                                             \
    PH_BAR();                                                                  \
  }

  // prologue: tiles 0 and 1 in flight (12 issues); wait tile 0 only
  G_STAGE_ALL(0, 0);
  ISSUE_FENCE();
  G_STAGE_ALL(1, 1);
  BARRIER_VM6();

  for (int t = 0; t < NT; ++t) {
    const int pf = (t + 2 < NT) ? t + 2 : NT - 1;  // dummy-clamp keeps vmcnt exact
    const int pb = (t + 2) % 3;
    const unsigned short* la = As[t % 3];
    const unsigned short* lb = Bs[t % 3];
    V4_PHASE(0, la, lb,
             { G_STAGE_A(pf, pb, 0); G_STAGE_A(pf, pb, 1); G_STAGE_B(pf, pb, 0); },
             PH_BAR());
    V4_PHASE(1, la, lb,
             { G_STAGE_A(pf, pb, 2); G_STAGE_A(pf, pb, 3); G_STAGE_B(pf, pb, 1); },
             BARRIER_VM6());
  }

#pragma unroll
  for (int mi = 0; mi < 4; ++mi) {
#pragma unroll
    for (int ni = 0; ni < 4; ++ni) {
      const int col = n0 + wn + ni * 16 + l16;
      const int row = m0 + wm + mi * 16 + quad * 4;
      const float bv = bias[col];
      const float sv = (col < scale_cols) ? scale_val : 1.0f;
#pragma unroll
      for (int r = 0; r < 4; ++r) {
        float v = (acc[mi][ni][r] + bv) * sv;
        if (OUT_F32)
          ((float*)C)[(size_t)(row + r) * N + col] = v;
        else
          ((unsigned short*)C)[(size_t)(row + r) * N + col] = f2b(v);
      }
    }
  }
}

// ---------------- flash attention v11 (merged barrier, Vt dbuf) ----------
// Round-12 post-mortem: 4 blocks/CU via distance-1 REGRESSED (70.3->72.7):
// occupancy rose 19.9->24.6 but the vmcnt(0) drain (loads issued only one
// compute-phase earlier, 16 waves contending) cost more. Occupancy is
// exhausted as a flash lever. REVERT to distance-2 K triple-buffer.
//
// Round-13 change: ONE barrier per iteration instead of two. Vt is now
// DOUBLE-buffered (+8 KB -> LDS 50176 B, still 3 blocks/CU), so the V
// publish needs no predecessor barrier:
//   iter i: prefetch slot i+2 ; compute tile i (reads Ks[i%3], Vt[i&1]) ;
//           VT_WRITE(Vt[(i+1)&1], slot i+1's V regs) ;
//           s_waitcnt vmcnt(4) lgkmcnt(0) ; s_barrier
// Sync proof:
//  - VT_WRITE's register use forces a vmcnt wait that drains the FIFO
//    through slot i+1 (its K gload_lds are OLDER than its V reg loads ->
//    drained too). Data was issued a full iteration (~2000 cyc) earlier ->
//    cheap. After the barrier, Ks[(i+1)%3] and Vt[(i+1)&1] are visible.
//  - WAR Vt[(i+1)&1]: last readers ran in compute(i-1), finished before
//    barrier(i-1); this write is after barrier(i-1). OK.
//  - WAR Ks[(i+2)%3]: readers were compute(i-1); prefetch(i+2) issues
//    after barrier(i-1). OK.
//  - vmcnt(4) at the barrier: outstanding is exactly slot i+2's 4 (slot
//    i+1 drained by VT_WRITE) -> free guard.
// Everything else identical to the round-11 best (1-D heavy-first grid,
// same-XCD (b,h) affinity, setprio, 4 vmem issues/iter).

// prefetch global slot g_ -> Ks[g_%3] + V regs (via_, vib_)
#define FA_PREFETCH(g_, via_, vib_)                                            \
  {                                                                            \
    const int _g = (g_);                                                       \
    const int _tg = (_g < kt) ? _g : 0;                                        \
    const unsigned short* _kg =                                                \
        base + (size_t)(_tg * 64 + ktok_l) * QKV_LD + DIM + h * HD + kchunk * 8; \
    gload_lds16(_kg, &Ks[_g % 3][0][w * 512]);                                 \
    gload_lds16(_kg + 32, &Ks[_g % 3][1][w * 512]);                            \
    const unsigned short* _vg =                                                \
        base + (size_t)(_tg * 64 + 2 * vk) * QKV_LD + 2 * DIM + h * HD + vc;   \
    via_ = *(const u16x8*)_vg;                                                 \
    vib_ = *(const u16x8*)(_vg + QKV_LD);                                      \
  }

#define VT_WRITE(buf_, va_, vb_)                                               \
  {                                                                            \
    u32a* _V32 = (u32a*)(Vt + (buf_) * 4096);                                  \
    _Pragma("unroll") for (int j = 0; j < 8; ++j)                              \
      _V32[vwidx[j]] = (unsigned int)(va_)[j] | ((unsigned int)(vb_)[j] << 16);\
  }

#define FA_COMPUTE(i_, t_, kt_, qf_)                                           \
  {                                                                            \
    const unsigned short* _kb0 = &Ks[(i_) % 3][0][0];                          \
    const unsigned short* _kb1 = &Ks[(i_) % 3][1][0];                          \
    const unsigned short* _vt = Vt + ((i_) & 1) * 4096;                        \
    bf16x8 kf0[4], kf1[4], vf0[4], vf1[4];                                     \
    _Pragma("unroll") for (int ni = 0; ni < 4; ++ni) {                         \
      const int ro = (ni * 16 + l16) * 32 + ((quad ^ rsw) * 8);                \
      kf0[ni] = ld_frag16(_kb0 + ro);                                          \
      kf1[ni] = ld_frag16(_kb1 + ro);                                          \
      vf0[ni] = ld_frag16(&_vt[quad * 512 + vroff[ni]]);                       \
      vf1[ni] = ld_frag16(&_vt[(4 + quad) * 512 + vroff[ni]]);                 \
    }                                                                          \
    const int qloc = w * 16 + quad * 4;                                        \
    __builtin_amdgcn_s_setprio(1);                                             \
    _Pragma("unroll") for (int m = 0; m < 2; ++m) {                            \
      if (!(m == 0 && (t_) == (kt_)-1)) { /* m=0 fully masked on last tile */  \
        const bool diag = ((t_) == (kt_)-2 + m);                               \
        _Pragma("unroll") for (int ni = 0; ni < 4; ++ni) {                     \
          f32x4 a = {};                                                        \
          a = __builtin_amdgcn_mfma_f32_16x16x32_bf16(qf_[m][0], kf0[ni], a, 0, 0, 0); \
          a = __builtin_amdgcn_mfma_f32_16x16x32_bf16(qf_[m][1], kf1[ni], a, 0, 0, 0); \
          const int kloc = ni * 16 + l16;                                      \
          _Pragma("unroll") for (int r = 0; r < 4; ++r) {                      \
            float p = __builtin_amdgcn_exp2f(a[r]);                            \
            if (diag && kloc > qloc + r) p = 0.0f; /* causal */                \
            Ps[w][(quad * 4 + r) * 72 + kloc] =                                \
                (unsigned short)(__builtin_bit_cast(unsigned int, p) >> 16);   \
          }                                                                    \
        }                                                                      \
        _Pragma("unroll") for (int c = 0; c < 2; ++c) {                        \
          const bf16x8 pa = ld_frag16(&Ps[w][l16 * 72 + c * 32 + quad * 8]);   \
          _Pragma("unroll") for (int ni = 0; ni < 4; ++ni)                     \
            o[m][ni] = __builtin_amdgcn_mfma_f32_16x16x32_bf16(                \
                pa, c ? vf1[ni] : vf0[ni], o[m][ni], 0, 0, 0);                 \
          lacc[m] = __builtin_amdgcn_mfma_f32_16x16x32_bf16(pa, onesb,         \
                                                            lacc[m], 0, 0, 0);\
        }                                                                      \
      }                                                                        \
    }                                                                          \
    __builtin_amdgcn_s_setprio(0);                                             \
  }

// one iteration: prefetch slot i+2 into (pva,pvb); compute tile i from
// Ks[i%3]/Vt[i&1]; publish slot i+1's V into Vt[(i+1)&1]; merged barrier.
#define FA_ITER(i_, t_, kt_, qf_, pva, pvb, cva, cvb)                          \
  {                                                                            \
    FA_PREFETCH((i_) + 2, pva, pvb);                                           \
    FA_COMPUTE(i_, t_, kt_, qf_);                                              \
    VT_WRITE((((i_) + 1) & 1), cva, cvb);                                      \
    BARRIER_VMLG();                                                            \
  }

#define FA_EPILOGUE(q0_)                                                       \
  _Pragma("unroll") for (int m = 0; m < 2; ++m)                                \
  _Pragma("unroll") for (int r = 0; r < 4; ++r) {                              \
    const float lv = __shfl(lacc[m][r], quad << 4);                            \
    const float inv = 1.0f / lv;                                               \
    const int row = (q0_) + m * 64 + w * 16 + quad * 4 + r;                    \
    unsigned short* dst = yatt + (size_t)(b * SEQ + row) * DIM + h * HD + l16; \
    _Pragma("unroll") for (int ni = 0; ni < 4; ++ni)                           \
      dst[ni * 16] = f2b(o[m][ni][r] * inv);                                   \
  }

__global__ __launch_bounds__(256, 2) void flash_kernel(
    const unsigned short* __restrict__ qkv,  // [B*S][3072] bf16 (q pre-scaled)
    unsigned short* __restrict__ yatt) {     // [B*S][1024] bf16
  __shared__ unsigned short Ks[3][2][64 * 32];                 // 24576 B
  __shared__ __align__(16) unsigned short Vt[2 * 8 * 64 * 8];  // 16384 B
  __shared__ __align__(16) unsigned short Ps[4][16 * 72];      //  9216 B

  const int tid = threadIdx.x;
  const int w = tid >> 6;
  const int lane = tid & 63;
  const int quad = lane >> 4;
  const int l16 = lane & 15;

  // 1-D grid, 1024 blocks: global heavy-first + same-XCD (b,h) affinity
  const int bid = (int)blockIdx.x;
  const int qt = 15 - (bid >> 6);  // 15..0, heavy first
  const int bh = bid & 63;
  const int b = bh >> 4;
  const int h = bh & 15;
  const int kt = 2 * qt + 2;       // 32..2, always even
  const int q0 = qt * 128;

  const unsigned short* base = qkv + (size_t)b * SEQ * QKV_LD;

  // K staging: wave w covers toks w*16..+15, both 32-dim halves
  const int ktok_l = w * 16 + (lane >> 2);
  const int ksw = (ktok_l ^ (ktok_l >> 2)) & 3;
  const int kchunk = (lane & 3) ^ ksw;
  const int rsw = (l16 ^ (l16 >> 2)) & 3;

  // V staging: thread covers toks {2vk,2vk+1}, dims vc..vc+7
  const int vk = tid >> 3;
  const int vc = (tid & 7) * 8;
  int vwidx[8];
#pragma unroll
  for (int j = 0; j < 8; ++j)
    vwidx[j] = (vk >> 2) * 256 + (vc | ((j + (vc >> 3)) & 7)) * 4 + (vk & 3);
  int vroff[4];
#pragma unroll
  for (int ni = 0; ni < 4; ++ni) {
    const int dim = ni * 16 + l16;
    vroff[ni] = ((dim & 56) | ((dim + (dim >> 3)) & 7)) * 8;
  }

  // ones B-fragment for MFMA row-sum (B[k][0]=1 lives in l16==0 lanes)
  u16x8 ob = {};
  if (l16 == 0) {
#pragma unroll
    for (int j = 0; j < 8; ++j) ob[j] = 0x3F80;  // bf16 1.0
  }
  const bf16x8 onesb = __builtin_bit_cast(bf16x8, ob);

  // Q A-fragments up front (loop stays at exactly 4 vmem issues/iter)
  bf16x8 qf[2][2];
#pragma unroll
  for (int m = 0; m < 2; ++m) {
    const unsigned short* qa =
        base + (size_t)(q0 + m * 64 + w * 16 + l16) * QKV_LD + h * HD + quad * 8;
    qf[m][0] = *(const bf16x8*)qa;
    qf[m][1] = *(const bf16x8*)(qa + 32);
  }

  // prologue: slots 0 and 1 in flight; publishing V tile 0 drains the FIFO
  // through slot 0 (qf + slot0 K included); barrier makes tile 0 visible.
  u16x8 va0, vb0, va1, vb1;
  ISSUE_FENCE();
  FA_PREFETCH(0, va0, vb0);
  ISSUE_FENCE();
  FA_PREFETCH(1, va1, vb1);
  VT_WRITE(0, va0, vb0);   // waits slot0 V -> slot0 K + qf drained (FIFO)
  BARRIER_LGKM();          // all waves' K/V tile 0 visible; slot1 in flight

  f32x4 o[2][4] = {};
  f32x4 lacc[2] = {};

  // kt is even, so the explicit V ping-pong stays aligned
  for (int i = 0; i < kt; i += 2) {
    FA_ITER(i,     i,     kt, qf, va0, vb0, va1, vb1);
    FA_ITER(i + 1, i + 1, kt, qf, va1, vb1, va0, vb0);
  }
  FA_EPILOGUE(q0);
}

// ---------------- launch ----------------

extern "C" void kernel_launch(void* const* d_in, const int* in_sizes, int n_in,
                              void* d_out, int out_size, void* d_ws, size_t ws_size,
                              hipStream_t stream) {
  const float* x  = (const float*)d_in[0];   // [4,2048,1024]
  const float* Wa = (const float*)d_in[1];   // [1024,3072]
  const float* ba = (const float*)d_in[2];   // [3072]
  const float* Wp = (const float*)d_in[3];   // [1024,1024]
  const float* bp = (const float*)d_in[4];   // [1024]
  float* out = (float*)d_out;                // [4,2048,1024] fp32

  char* ws = (char*)d_ws;
  unsigned short* xb   = (unsigned short*)ws;                   // 16,777,216 B
  unsigned short* WaT  = (unsigned short*)(ws + 16777216);      //  6,291,456 B
  unsigned short* WpT  = (unsigned short*)(ws + 23068672);      //  2,097,152 B
  unsigned short* qkv  = (unsigned short*)(ws + 25165824);      // 50,331,648 B
  unsigned short* yatt = (unsigned short*)(ws + 75497472);      // 16,777,216 B

  const int M = 4 * SEQ;  // 8192
  const float qscale = 0.125f * 1.44269504089f;  // 1/sqrt(64) * log2(e)

  // fused pre-pass: 8192 (to_bf16) + 3072 (Wa^T) + 1024 (Wp^T) blocks
  prep_kernel<<<12288, 256, 0, stream>>>(x, xb, M * DIM, Wa, WaT, Wp, WpT);

  gemm_bt_v4_kernel<0><<<dim3(24, 32), 512, 0, stream>>>(xb, WaT, ba, qkv, M, 3 * DIM, DIM,
                                                         DIM, qscale);

  flash_kernel<<<dim3(1024), 256, 0, stream>>>(qkv, yatt);

  gemm_bt_v4_kernel<1><<<dim3(8, 32), 512, 0, stream>>>(yatt, WpT, bp, out, M, DIM, DIM,
                                                        0, 1.0f);
}